// Round 6
// baseline (264.535 us; speedup 1.0000x reference)
//
#include <hip/hip_runtime.h>
#include <stdint.h>

#define TT 512
#define BT 16   // 4096/16 = 256 wgs = 1 wg/CU (occupancy pinned: 1024 waves)

typedef float    f32x4 __attribute__((ext_vector_type(4)));
typedef float    f32x2 __attribute__((ext_vector_type(2)));
typedef short    s16x8 __attribute__((ext_vector_type(8)));
typedef _Float16 f16x8 __attribute__((ext_vector_type(8)));

#define MFMA_F16(A, B, C) \
    __builtin_amdgcn_mfma_f32_16x16x32_f16( \
        __builtin_bit_cast(f16x8, (A)), (B), (C), 0, 0, 0)

#define LOG2E  1.442695040888963f
#define LOG2E2 2.885390081777927f
#define MAGIC  12582912.0f   // 1.5 * 2^23 : round-to-nearest-int trick

static __device__ __forceinline__ unsigned bits(float v) {
    union { float f; unsigned u; } x; x.f = v; return x.u;
}
static __device__ __forceinline__ float fbits(unsigned u) {
    union { unsigned u; float f; } x; x.u = u; return x.f;
}

// packed 2^a for a in [-30, 30]: magic-round + deg-4 Taylor + exponent add.
// All main-pipe (pk_fma / int): no trans ops. rel err ~4e-5.
static __device__ __forceinline__ f32x2 exp2_pk(f32x2 a) {
    f32x2 r0 = a + MAGIC;            // mantissa holds int(a)
    f32x2 fi = r0 - MAGIC;           // rounded-to-nearest integer value
    f32x2 f  = a - fi;               // f in [-0.5, 0.5]
    f32x2 p  = f * 0.00961813f + 0.05550411f;
    p = p * f + 0.24022651f;
    p = p * f + 0.69314718f;
    p = p * f + 1.0f;
    unsigned e0 = (bits(r0[0]) << 23) + bits(p[0]);   // exact 2^i scale
    unsigned e1 = (bits(r0[1]) << 23) + bits(p[1]);
    f32x2 E = {fbits(e0), fbits(e1)};
    return E;
}

// packed 1/x for normal positive x: magic guess + 2 Newton iters, rel err ~6e-6
static __device__ __forceinline__ f32x2 rcp_pk(f32x2 x) {
    f32x2 y = {fbits(0x7EF311C3u - bits(x[0])), fbits(0x7EF311C3u - bits(x[1]))};
    y = y * (2.0f - x * y);
    y = y * (2.0f - x * y);
    return y;
}

// BT=16, 4 waves, wave w owns hidden cols [16w,16w+16). fp16 MFMA: 6/step.
// W_hh in registers; h exchanged via LDS (fp16, swizzled A-frag order,
// double-buffered, 1 barrier/step). ALL transcendentals replaced by packed
// main-pipe sequences (trans issue = 16 cyc/wave64 was 320 of 379 VALU cyc).
// h-write layout: slot = kg*16 + (perm(m) ^ 4*(kg&1)), perm(m)=(m&3)*4+(m>>2)
// -> 64 b16 writes hit 32 banks 2-per-dword (was 8-way conflict); readers
// still load contiguous b128 since kg&1 == quad&1 for reader lanes.
__global__ __launch_bounds__(256) void gru_scan_kernel(
    const float* __restrict__ x,     // (4096, 512, 1)
    const float* __restrict__ Wih,   // (192, 1)
    const float* __restrict__ Whh,   // (192, 64)
    const float* __restrict__ bih,   // (192)
    const float* __restrict__ bhh,   // (192)
    const float* __restrict__ Wout,  // (1, 64)
    const float* __restrict__ bout,  // (1)
    float* __restrict__ out)         // (4096, 1)
{
    __shared__ __align__(16) float xs2[TT * BT];   // x transposed [t][b], 32 KB
    __shared__ __align__(16) short hbuf[2][1024];  // [dbuf][slot*8+j], 4 KB
    __shared__ float outp[4][BT];

    const int tid  = threadIdx.x;
    const int w    = tid >> 6;
    const int L    = tid & 63;
    const int n16  = L & 15;
    const int quad = L >> 4;
    const int q    = w * 16 + n16;   // hidden col owned by this lane
    const int b0   = blockIdx.x * BT;

    // ---- stage x transposed: xs2[t][b] ----
    #pragma unroll
    for (int k = 0; k < 8; ++k) {
        int idx = tid + k * 256;
        int row = idx >> 7;               // batch row 0..15
        int t4  = idx & 127;              // t/4
        f32x4 v = *(const f32x4*)(x + (size_t)(b0 + row) * TT + t4 * 4);
        #pragma unroll
        for (int i = 0; i < 4; ++i)
            xs2[(t4 * 4 + i) * BT + row] = v[i];
    }
    // ---- zero both h double-buffers ----
    {
        f32x4* hb = (f32x4*)hbuf;   // 4096 B = 256 f32x4
        f32x4 zv = {0.f, 0.f, 0.f, 0.f};
        hb[tid] = zv;
    }

    // ---- per-lane constants (gate scales folded) ----
    const float wr2   = -LOG2E  * Wih[q];
    const float wz2   = -LOG2E  * Wih[64 + q];
    const float wn2   =  LOG2E2 * Wih[128 + q];
    const float bR2   = -LOG2E  * (bih[q]      + bhh[q]);
    const float bZ2   = -LOG2E  * (bih[64 + q] + bhh[64 + q]);
    const float bN2   =  LOG2E2 * bhh[128 + q];
    const float bihn2 =  LOG2E2 * bih[128 + q];
    const float wo    = Wout[q];

    const f32x4 bR4 = {bR2, bR2, bR2, bR2};
    const f32x4 bZ4 = {bZ2, bZ2, bZ2, bZ2};
    const f32x4 bN4 = {bN2, bN2, bN2, bN2};

    // ---- W_hh B-fragments (scaled), fp16 RNE ----
    f16x8 Bf[3][2];
    #pragma unroll
    for (int g = 0; g < 3; ++g) {
        const float sg = (g == 2) ? LOG2E2 : -LOG2E;
        #pragma unroll
        for (int c = 0; c < 2; ++c) {
            const float* p = Whh + ((g * 64 + q) * 64 + c * 32 + quad * 8);
            #pragma unroll
            for (int j = 0; j < 8; ++j)
                Bf[g][c][j] = (_Float16)(p[j] * sg);
        }
    }

    // persistent h (fp32), D-layout: reg -> (m = quad*4+reg, col q)
    float hD[4] = {0.f, 0.f, 0.f, 0.f};

    // ---- swizzled LDS addressing ----
    // writer: for reg r, m = quad*4+r, k = q:
    //   slot = kg*16 + ((r*4+quad) ^ sxor), addr = slot*8 + (q&7)
    const int kg   = q >> 3;
    const int sxor = (kg & 1) * 4;
    int waddr[4];
    #pragma unroll
    for (int r = 0; r < 4; ++r)
        waddr[r] = (kg * 16 + ((r * 4 + quad) ^ sxor)) * 8 + (q & 7);

    // reader: chunk c -> slot index cur*128 + c*64 + quad*16 + permx
    const int permx = ((n16 & 3) * 4 + (n16 >> 2)) ^ ((quad & 1) * 4);
    const int rslot = quad * 16 + permx;

    const s16x8* hbv = (const s16x8*)hbuf;   // 256 slots of 8 shorts

    auto step = [&](int cur, int t) {
        __syncthreads();

        s16x8 A0 = hbv[cur * 128 +  0 + rslot];
        s16x8 A1 = hbv[cur * 128 + 64 + rslot];
        f32x4 xq = *(const f32x4*)(xs2 + t * BT + quad * 4);  // per-quad bcast

        f32x4 aR = MFMA_F16(A0, Bf[0][0], bR4);
        aR       = MFMA_F16(A1, Bf[0][1], aR);
        f32x4 aN = MFMA_F16(A0, Bf[2][0], bN4);
        aN       = MFMA_F16(A1, Bf[2][1], aN);
        f32x4 aZ = MFMA_F16(A0, Bf[1][0], bZ4);
        aZ       = MFMA_F16(A1, Bf[1][1], aZ);

        short* wh = (short*)hbuf + (cur ^ 1) * 1024;

        #pragma unroll
        for (int p = 0; p < 4; p += 2) {
            f32x2 aRp = {aR[p], aR[p + 1]};
            f32x2 aZp = {aZ[p], aZ[p + 1]};
            f32x2 aNp = {aN[p], aN[p + 1]};
            f32x2 xv  = {xq[p], xq[p + 1]};
            f32x2 hp  = {hD[p], hD[p + 1]};

            f32x2 ar = xv * wr2 + aRp;
            f32x2 az = xv * wz2 + aZp;
            f32x2 xn = xv * wn2 + bihn2;

            f32x2 Er = exp2_pk(ar);
            f32x2 Ez = exp2_pk(az);
            f32x2 DR = Er + 1.0f;
            f32x2 DZ = Ez + 1.0f;
            f32x2 r  = rcp_pk(DR);              // sigmoid(pre_r)
            f32x2 an = r * aNp + xn;
            f32x2 En = exp2_pk(an);
            f32x2 DN = En + 1.0f;
            f32x2 P  = DZ * DN;
            f32x2 iq = rcp_pk(P);
            // hn = z*hp + (1-z)*n, z=1/DZ, n=1-2/DN
            //    = iq*((hp-1)*DN + 2 - 2*DZ) + 1
            f32x2 s2 = 2.0f - 2.0f * DZ;
            f32x2 tt = (hp - 1.0f) * DN + s2;
            f32x2 hn = iq * tt + 1.0f;

            hD[p] = hn[0]; hD[p + 1] = hn[1];

            wh[waddr[p]]     = __builtin_bit_cast(short, (_Float16)hn[0]);
            wh[waddr[p + 1]] = __builtin_bit_cast(short, (_Float16)hn[1]);
        }
    };

    for (int t = 0; t < TT; t += 2) {
        step(0, t);
        step(1, t + 1);
    }

    // ---- epilogue: out[b] = sum_q h[b][q]*Wout[q] + bout ----
    float p[4];
    #pragma unroll
    for (int reg = 0; reg < 4; ++reg) p[reg] = hD[reg] * wo;
    #pragma unroll
    for (int mask = 1; mask <= 8; mask <<= 1) {
        #pragma unroll
        for (int reg = 0; reg < 4; ++reg)
            p[reg] += __shfl_xor(p[reg], mask, 64);
    }
    if (n16 == 0) {
        #pragma unroll
        for (int reg = 0; reg < 4; ++reg)
            outp[w][quad * 4 + reg] = p[reg];
    }
    __syncthreads();
    if (tid < BT) {
        out[b0 + tid] = outp[0][tid] + outp[1][tid] + outp[2][tid] + outp[3][tid] + bout[0];
    }
}

extern "C" void kernel_launch(void* const* d_in, const int* in_sizes, int n_in,
                              void* d_out, int out_size, void* d_ws, size_t ws_size,
                              hipStream_t stream) {
    (void)in_sizes; (void)n_in; (void)d_ws; (void)ws_size; (void)out_size;
    const float* x    = (const float*)d_in[0];
    const float* Wih  = (const float*)d_in[1];
    const float* Whh  = (const float*)d_in[2];
    const float* bih  = (const float*)d_in[3];
    const float* bhh  = (const float*)d_in[4];
    const float* Wout = (const float*)d_in[5];
    const float* bout = (const float*)d_in[6];
    float* out = (float*)d_out;

    gru_scan_kernel<<<dim3(4096 / BT), dim3(256), 0, stream>>>(
        x, Wih, Whh, bih, bhh, Wout, bout, out);
}

// Round 7
// 200.793 us; speedup vs baseline: 1.3175x; 1.3175x over previous
//
#include <hip/hip_runtime.h>
#include <stdint.h>

#define TT 512
#define BT 8    // 4096/8 = 512 wgs -> 2 wgs/CU -> 2 waves/SIMD (no dup work)

typedef float    f32x4 __attribute__((ext_vector_type(4)));
typedef float    f32x2 __attribute__((ext_vector_type(2)));
typedef short    s16x8 __attribute__((ext_vector_type(8)));
typedef _Float16 f16x8 __attribute__((ext_vector_type(8)));

#define MFMA_F16(A, B, C) \
    __builtin_amdgcn_mfma_f32_16x16x32_f16( \
        __builtin_bit_cast(f16x8, (A)), (B), (C), 0, 0, 0)

#define LOG2E  1.442695040888963f
#define LOG2E2 2.885390081777927f

// 256 threads = 4 waves; wave w owns hidden cols [16w,16w+16). fp16 MFMA,
// 6/step/wave. BT=8: batches mapped to D-rows {0,1,4,5,8,9,12,13}
// (m = (b>>1)*4 + (b&1)) so each lane's valid accumulators are exactly regs
// {0,1}: all 64 lanes do elementwise (1 packed f32x2 pair), nothing idle,
// nothing duplicated. 2 wgs/CU co-schedule: one wg's VALU hides the other's
// MFMA/LDS latency. h exchanged via LDS (fp16, swizzled A-frag order,
// double-buffered, 1 barrier/step); unwritten rows stay zero (never read).
// HW exp2/rcp (4 cyc/wave64 issue — manual poly was slower, R6).
__global__ __launch_bounds__(256, 2) void gru_scan_kernel(
    const float* __restrict__ x,     // (4096, 512, 1)
    const float* __restrict__ Wih,   // (192, 1)
    const float* __restrict__ Whh,   // (192, 64)
    const float* __restrict__ bih,   // (192)
    const float* __restrict__ bhh,   // (192)
    const float* __restrict__ Wout,  // (1, 64)
    const float* __restrict__ bout,  // (1)
    float* __restrict__ out)         // (4096, 1)
{
    __shared__ __align__(16) float xs2[TT * BT];   // x transposed [t][b], 16 KB
    __shared__ __align__(16) short hbuf[2][1024];  // [dbuf][slot*8+j], 4 KB
    __shared__ float outp[4][BT];

    const int tid  = threadIdx.x;
    const int w    = tid >> 6;
    const int L    = tid & 63;
    const int n16  = L & 15;
    const int quad = L >> 4;
    const int q    = w * 16 + n16;   // hidden col owned by this lane
    const int b0   = blockIdx.x * BT;

    // ---- stage x transposed: xs2[t][b] (8 rows x 512) ----
    #pragma unroll
    for (int k = 0; k < 4; ++k) {
        int idx = tid + k * 256;          // 0..1023
        int row = idx >> 7;               // batch row 0..7
        int t4  = idx & 127;              // t/4
        f32x4 v = *(const f32x4*)(x + (size_t)(b0 + row) * TT + t4 * 4);
        #pragma unroll
        for (int i = 0; i < 4; ++i)
            xs2[(t4 * 4 + i) * BT + row] = v[i];
    }
    // ---- zero both h double-buffers (4 KB = 256 f32x4) ----
    {
        f32x4* hb = (f32x4*)hbuf;
        f32x4 zv = {0.f, 0.f, 0.f, 0.f};
        hb[tid] = zv;
    }

    // ---- per-lane constants (gate scales folded) ----
    const float wr2   = -LOG2E  * Wih[q];
    const float wz2   = -LOG2E  * Wih[64 + q];
    const float wn2   =  LOG2E2 * Wih[128 + q];
    const float bR2   = -LOG2E  * (bih[q]      + bhh[q]);
    const float bZ2   = -LOG2E  * (bih[64 + q] + bhh[64 + q]);
    const float bN2   =  LOG2E2 * bhh[128 + q];
    const float bihn2 =  LOG2E2 * bih[128 + q];
    const float wo    = Wout[q];

    const f32x4 bR4 = {bR2, bR2, bR2, bR2};
    const f32x4 bZ4 = {bZ2, bZ2, bZ2, bZ2};
    const f32x4 bN4 = {bN2, bN2, bN2, bN2};

    // ---- W_hh B-fragments (scaled), fp16 RNE ----
    f16x8 Bf[3][2];
    #pragma unroll
    for (int g = 0; g < 3; ++g) {
        const float sg = (g == 2) ? LOG2E2 : -LOG2E;
        #pragma unroll
        for (int c = 0; c < 2; ++c) {
            const float* p = Whh + ((g * 64 + q) * 64 + c * 32 + quad * 8);
            #pragma unroll
            for (int j = 0; j < 8; ++j)
                Bf[g][c][j] = (_Float16)(p[j] * sg);
        }
    }

    // persistent h (fp32): lane handles batches b = quad*2 + {0,1}
    // (D rows m = quad*4 + {0,1}; rows with m&3 >= 2 unused, stay zero)
    float hD[2] = {0.f, 0.f};

    // ---- swizzled LDS addressing (R6 scheme, proven -4.2e6 conflicts) ----
    // writer: batch b -> row m=(b>>1)*4+(b&1); for p in {0,1}, m=quad*4+p:
    //   slot = kg*16 + ((p*4+quad) ^ sxor), addr = slot*8 + (q&7)
    const int kg   = q >> 3;
    const int sxor = (kg & 1) * 4;
    int waddr[2];
    #pragma unroll
    for (int p = 0; p < 2; ++p)
        waddr[p] = (kg * 16 + ((p * 4 + quad) ^ sxor)) * 8 + (q & 7);

    // reader: slot = quad*16 + (perm(n16) ^ (quad&1)*4)
    const int permx = ((n16 & 3) * 4 + (n16 >> 2)) ^ ((quad & 1) * 4);
    const int rslot = quad * 16 + permx;

    const s16x8* hbv = (const s16x8*)hbuf;   // 256 slots of 8 shorts

    auto step = [&](int cur, int t) {
        __syncthreads();

        s16x8 A0 = hbv[cur * 128 +  0 + rslot];
        s16x8 A1 = hbv[cur * 128 + 64 + rslot];
        f32x2 xv = *(const f32x2*)(xs2 + t * BT + quad * 2);  // 2 batches' x

        // r-gate first (heads the serial chain), z last
        f32x4 aR = MFMA_F16(A0, Bf[0][0], bR4);
        aR       = MFMA_F16(A1, Bf[0][1], aR);
        f32x4 aN = MFMA_F16(A0, Bf[2][0], bN4);
        aN       = MFMA_F16(A1, Bf[2][1], aN);
        f32x4 aZ = MFMA_F16(A0, Bf[1][0], bZ4);
        aZ       = MFMA_F16(A1, Bf[1][1], aZ);

        short* wh = (short*)hbuf + (cur ^ 1) * 1024;

        // one packed pair: regs 0,1 = batches quad*2 + {0,1}
        f32x2 aRp = {aR[0], aR[1]};
        f32x2 aZp = {aZ[0], aZ[1]};
        f32x2 aNp = {aN[0], aN[1]};
        f32x2 hp  = {hD[0], hD[1]};

        f32x2 ar = xv * wr2 + aRp;
        f32x2 Er = {__builtin_amdgcn_exp2f(ar[0]), __builtin_amdgcn_exp2f(ar[1])};
        f32x2 DR = Er + 1.0f;
        f32x2 r  = {__builtin_amdgcn_rcpf(DR[0]), __builtin_amdgcn_rcpf(DR[1])};
        f32x2 az = xv * wz2 + aZp;
        f32x2 Ez = {__builtin_amdgcn_exp2f(az[0]), __builtin_amdgcn_exp2f(az[1])};
        f32x2 DZ = Ez + 1.0f;
        f32x2 xn = xv * wn2 + bihn2;
        f32x2 an = r * aNp + xn;
        f32x2 En = {__builtin_amdgcn_exp2f(an[0]), __builtin_amdgcn_exp2f(an[1])};
        f32x2 DN = En + 1.0f;
        f32x2 P  = DZ * DN;
        f32x2 iq = {__builtin_amdgcn_rcpf(P[0]), __builtin_amdgcn_rcpf(P[1])};
        f32x2 z  = iq * DN;                  // = 1/DZ = sigmoid(pre_z)
        f32x2 rn = iq * DZ;                  // = 1/DN
        f32x2 n  = rn * -2.0f + 1.0f;        // tanh
        f32x2 hn = z * (hp - n) + n;         // (1-z)n + z h

        hD[0] = hn[0]; hD[1] = hn[1];

        wh[waddr[0]] = __builtin_bit_cast(short, (_Float16)hn[0]);
        wh[waddr[1]] = __builtin_bit_cast(short, (_Float16)hn[1]);
    };

    for (int t = 0; t < TT; t += 2) {
        step(0, t);
        step(1, t + 1);
    }

    // ---- epilogue: out[b] = sum_q h[b][q]*Wout[q] + bout ----
    float p0 = hD[0] * wo;
    float p1 = hD[1] * wo;
    #pragma unroll
    for (int mask = 1; mask <= 8; mask <<= 1) {
        p0 += __shfl_xor(p0, mask, 64);
        p1 += __shfl_xor(p1, mask, 64);
    }
    if (n16 == 0) {
        outp[w][quad * 2]     = p0;
        outp[w][quad * 2 + 1] = p1;
    }
    __syncthreads();
    if (tid < BT) {
        out[b0 + tid] = outp[0][tid] + outp[1][tid] + outp[2][tid] + outp[3][tid] + bout[0];
    }
}

extern "C" void kernel_launch(void* const* d_in, const int* in_sizes, int n_in,
                              void* d_out, int out_size, void* d_ws, size_t ws_size,
                              hipStream_t stream) {
    (void)in_sizes; (void)n_in; (void)d_ws; (void)ws_size; (void)out_size;
    const float* x    = (const float*)d_in[0];
    const float* Wih  = (const float*)d_in[1];
    const float* Whh  = (const float*)d_in[2];
    const float* bih  = (const float*)d_in[3];
    const float* bhh  = (const float*)d_in[4];
    const float* Wout = (const float*)d_in[5];
    const float* bout = (const float*)d_in[6];
    float* out = (float*)d_out;

    gru_scan_kernel<<<dim3(4096 / BT), dim3(256), 0, stream>>>(
        x, Wih, Whh, bih, bhh, Wout, bout, out);
}